// Round 4
// baseline (228.778 us; speedup 1.0000x reference)
//
#include <hip/hip_runtime.h>
#include <stdint.h>

// GeometricBilinear (PGA 3,0,1) — MFMA formulation, R4.
// Per block: 16 positions, 256 threads (4 waves).
// stage0: per-wave direct global->register B-frag build (no LDS, no barrier)
// stage1: 4 equi-linears as per-component GEMMs (wave = one of L/R/JL/JR)
// stage2: channel-local gp/join bilinear on VALU (exchange via LDS)
// stage3: output equi-linear + scalar head on MFMA (hidden aliased into same LDS)

#define NPOS_TOTAL 32768

typedef __attribute__((ext_vector_type(8))) short short8;
typedef __attribute__((ext_vector_type(4))) float f32x4;
#define MFMA16(a,b,c) __builtin_amdgcn_mfma_f32_16x16x32_bf16((a),(b),(c),0,0,0)

// ---------------- constexpr PGA(3,0,1) blade tables (verified R1/R3) ----------------
constexpr int BLADE_MASK[16] = {0,1,2,4,8,3,5,9,6,10,12,7,11,13,14,15};
constexpr int MASK2IDX[16]   = {0,1,2,5,3,6,8,11,4,7,9,12,10,13,14,15};

struct MulRes { int sign; int mask; };

constexpr MulRes mul_blades(int ma, int mb) {
  int lst[8] = {0,0,0,0,0,0,0,0};
  int n = 0;
  for (int g = 0; g < 4; ++g) if ((ma >> g) & 1) lst[n++] = g;
  for (int g = 0; g < 4; ++g) if ((mb >> g) & 1) lst[n++] = g;
  int sign = 1;
  bool changed = true;
  while (changed) {
    changed = false;
    int k = 0;
    while (k + 1 < n) {
      if (lst[k] > lst[k+1]) {
        int t = lst[k]; lst[k] = lst[k+1]; lst[k+1] = t;
        sign = -sign; changed = true;
      } else if (lst[k] == lst[k+1]) {
        if (lst[k] == 0) sign = 0;            // METRIC = [0,1,1,1]
        for (int m = k; m + 2 < n; ++m) lst[m] = lst[m+2];
        n -= 2; changed = true;
      } else {
        ++k;
      }
    }
  }
  int mask = 0;
  for (int m = 0; m < n; ++m) mask |= (1 << lst[m]);
  if (sign == 0) mask = 0;
  return MulRes{sign, mask};
}

struct Tables {
  float gp_sgn[16][16]; int gp_idx[16][16];
  float jn_sgn[16][16]; int jn_idx[16][16];
  constexpr Tables() : gp_sgn{}, gp_idx{}, jn_sgn{}, jn_idx{} {
    for (int j = 0; j < 16; ++j) {
      for (int k = 0; k < 16; ++k) {
        MulRes r = mul_blades(BLADE_MASK[j], BLADE_MASK[k]);
        gp_sgn[j][k] = (float)r.sign;
        gp_idx[j][k] = MASK2IDX[r.mask & 15];
        jn_sgn[j][k] = 0.0f; jn_idx[j][k] = 0;
        int mb = BLADE_MASK[j], mc = BLADE_MASK[k];
        if ((mb | mc) == 15) {
          int cb = 15 ^ mb, cc = 15 ^ mc;
          MulRes sb = mul_blades(mb, cb);
          MulRes sc = mul_blades(mc, cc);
          MulRes ro = mul_blades(cb, cc);
          int imask = ro.mask;
          int amask = 15 ^ imask;
          MulRes si = mul_blades(imask, amask);
          jn_sgn[j][k] = (float)(si.sign * ro.sign * sb.sign * sc.sign);
          jn_idx[j][k] = MASK2IDX[amask & 15];
        }
      }
    }
  }
};
constexpr Tables TBL{};

constexpr int GRADE[16] = {0,1,1,1,1,2,2,2,2,2,2,3,3,3,3,4};
constexpr int E0_TGT[8]  = {1,5,6,7,11,12,13,15};
constexpr int E0_SRC[8]  = {0,2,3,4,8,9,10,14};
constexpr int E0_SLOT[8] = {5,6,6,6,7,7,7,8};

// ---------------- helpers (manual RNE bf16 pack — verified) ----------------
__device__ __forceinline__ float bflo(unsigned u) { return __uint_as_float(u << 16); }
__device__ __forceinline__ float bfhi(unsigned u) { return __uint_as_float(u & 0xffff0000u); }
__device__ __forceinline__ unsigned pk2(float a, float b) {
  unsigned ua = __float_as_uint(a), ub = __float_as_uint(b);
  unsigned ra = (ua + 0x7fffu + ((ua >> 16) & 1u)) >> 16;   // RNE
  unsigned rb = (ub + 0x7fffu + ((ub >> 16) & 1u)) >> 16;
  return (ra & 0xffffu) | ((rb & 0xffffu) << 16);
}
__device__ __forceinline__ unsigned short bf1(float a) {
  unsigned ua = __float_as_uint(a);
  return (unsigned short)((ua + 0x7fffu + ((ua >> 16) & 1u)) >> 16);
}

// yl (stage1<->2 exchange) u32 addressing: rows o=0..63, pos, jp=0..7 (comp pairs)
// stride tuned so both writer-lane o-groups (delta 4) and reader rows (delta 16)
// land 8 banks apart.
__device__ __forceinline__ int YL(int o, int pos, int jp) {
  return o * 162 + (o >> 4) * 8 + pos * 10 + jp;
}
// hl (stage2->3 hidden) u32 addressing (aliased into same buffer): [pos][j][ch2]
#define HL_U32(pos, j, ch2) ((pos) * 272 + (j) * 16 + (ch2))

// ---------------- prep: pack all A-fragments (bf16) into ws (unchanged R3) ----------------
__global__ void gb_prep(const float* __restrict__ wlmv, const float* __restrict__ wrmv,
                        const float* __restrict__ wjlmv, const float* __restrict__ wjrmv,
                        const float* __restrict__ wls,  const float* __restrict__ wrs,
                        const float* __restrict__ wjls, const float* __restrict__ wjrs,
                        const float* __restrict__ womv, const float* __restrict__ ws2mv,
                        const float* __restrict__ wm2s, const float* __restrict__ ws2s,
                        uint4* __restrict__ wpk) {
  int t = blockIdx.x * 256 + threadIdx.x;
  if (t >= 168 * 64) return;
  int blk = t >> 6, l = t & 63;
  int m = l & 15, q = l >> 4;
  float v[8];
  if (blk < 104) {
    int mat = blk >> 2, ot = blk & 3;
    const float* wmv[4] = {wlmv, wrmv, wjlmv, wjrmv};
    const float* wsc[4] = {wls, wrs, wjls, wjrs};
    for (int jj = 0; jj < 8; ++jj) {
      int k = q * 8 + jj;
      if (mat < 16)      v[jj] = wmv[ot][m * 288 + k * 9 + GRADE[mat]];
      else if (mat < 24) v[jj] = wmv[ot][m * 288 + k * 9 + E0_SLOT[mat - 16]];
      else               v[jj] = wsc[ot][m * 64 + (mat - 24) * 32 + k];
    }
  } else if (blk < 156) {
    int b2 = blk - 104, mat = b2 >> 1, ot = b2 & 1;
    int o = ot * 16 + m;
    for (int jj = 0; jj < 8; ++jj) {
      int k = q * 8 + jj;
      if (mat < 16)      v[jj] = womv[o * 288 + k * 9 + GRADE[mat]];
      else if (mat < 24) v[jj] = womv[o * 288 + k * 9 + E0_SLOT[mat - 16]];
      else               v[jj] = ws2mv[o * 64 + (mat - 24) * 32 + k];
    }
  } else {
    int b4 = blk - 156;
    for (int jj = 0; jj < 8; ++jj) {
      int k = q * 8 + jj;
      if (b4 < 4) { int o = b4 * 16 + m; v[jj] = wm2s[o * 32 + k]; }
      else { int half = (b4 - 4) >> 2, ot = (b4 - 4) & 3; int o = ot * 16 + m;
             v[jj] = ws2s[o * 64 + half * 32 + k]; }
    }
  }
  uint4 u;
  u.x = pk2(v[0], v[1]); u.y = pk2(v[2], v[3]);
  u.z = pk2(v[4], v[5]); u.w = pk2(v[6], v[7]);
  wpk[t] = u;
}

// ---------------- main fused kernel ----------------
__global__ __launch_bounds__(256, 3) void gb_main(
    const float* __restrict__ mv, const float* __restrict__ ref,
    const float* __restrict__ s, const uint4* __restrict__ wpk,
    float* __restrict__ out_mv, float* __restrict__ out_s) {
  // Single LDS buffer: stage1->2 exchange (yl, 10388 u32 = 41.5 KB),
  // then reused (after barrier) as hidden [pos][j][ch2] (4336 u32).
  __shared__ __align__(16) unsigned smem_u32[10392];
  unsigned short* smem_us = (unsigned short*)smem_u32;

  const int tid  = threadIdx.x;
  const int wave = tid >> 6, lane = tid & 63;
  const int lm = lane & 15, lq = lane >> 4;
  const int P0 = blockIdx.x * 16;

  // ---- stage 0: per-wave direct global -> B-frag registers (bf16) ----
  // lane (lm,lq) needs x[pos=P0+lm][i=lq*8 .. lq*8+7][j=0..15] = 128 contiguous floats.
  uint4 bxu[16];
  {
    const float4* xb = (const float4*)(mv + (size_t)(P0 + lm) * 512 + lq * 128);
    #pragma unroll
    for (int p = 0; p < 4; ++p) {          // i-pair (2p, 2p+1)
      float4 A[4], B[4];
      #pragma unroll
      for (int q = 0; q < 4; ++q) { A[q] = xb[p * 8 + q]; B[q] = xb[p * 8 + 4 + q]; }
      float af[16], bf[16];
      #pragma unroll
      for (int q = 0; q < 4; ++q) {
        af[q*4+0] = A[q].x; af[q*4+1] = A[q].y; af[q*4+2] = A[q].z; af[q*4+3] = A[q].w;
        bf[q*4+0] = B[q].x; bf[q*4+1] = B[q].y; bf[q*4+2] = B[q].z; bf[q*4+3] = B[q].w;
      }
      #pragma unroll
      for (int j = 0; j < 16; ++j) {
        unsigned u = pk2(af[j], bf[j]);
        if      (p == 0) bxu[j].x = u;
        else if (p == 1) bxu[j].y = u;
        else if (p == 2) bxu[j].z = u;
        else             bxu[j].w = u;
      }
    }
  }

  // ---- s B-fragments (K=64 -> 2 frags): pos=lm, k=half*32+lq*8+jj ----
  short8 sfrag[2];
  {
    const float4* s4 = (const float4*)s + ((size_t)(P0 + lm)) * 16;
    #pragma unroll
    for (int h = 0; h < 2; ++h) {
      float4 a = s4[h * 8 + lq * 2];
      float4 b = s4[h * 8 + lq * 2 + 1];
      uint4 u;
      u.x = pk2(a.x, a.y); u.y = pk2(a.z, a.w);
      u.z = pk2(b.x, b.y); u.w = pk2(b.z, b.w);
      sfrag[h] = __builtin_bit_cast(short8, u);
    }
  }

  // ---- stage 1: this wave computes matrix `wave` (L/R/JL/JR) for 16 pos ----
  {
    f32x4 zf = {0.f, 0.f, 0.f, 0.f};
    f32x4 acc[16];
    #pragma unroll
    for (int j = 0; j < 16; ++j) acc[j] = zf;
    #pragma unroll
    for (int j = 0; j < 16; ++j) {
      short8 w = __builtin_bit_cast(short8, wpk[(j * 4 + wave) * 64 + lane]);
      acc[j] = MFMA16(w, __builtin_bit_cast(short8, bxu[j]), acc[j]);
    }
    #pragma unroll
    for (int m = 0; m < 8; ++m) {
      short8 w = __builtin_bit_cast(short8, wpk[((16 + m) * 4 + wave) * 64 + lane]);
      acc[E0_TGT[m]] = MFMA16(w, __builtin_bit_cast(short8, bxu[E0_SRC[m]]), acc[E0_TGT[m]]);
    }
    #pragma unroll
    for (int h = 0; h < 2; ++h) {
      short8 w = __builtin_bit_cast(short8, wpk[((24 + h) * 4 + wave) * 64 + lane]);
      acc[0] = MFMA16(w, sfrag[h], acc[0]);
    }
    // D-frag: lane holds out[o = wave*16 + lq*4 + r][pos = lm]; comp pairs -> yl
    #pragma unroll
    for (int r = 0; r < 4; ++r) {
      int o = wave * 16 + lq * 4 + r;
      int base = YL(o, lm, 0);
      #pragma unroll
      for (int jp2 = 0; jp2 < 4; ++jp2) {
        uint2 v;
        v.x = pk2(acc[4*jp2 + 0][r], acc[4*jp2 + 1][r]);
        v.y = pk2(acc[4*jp2 + 2][r], acc[4*jp2 + 3][r]);
        *(uint2*)&smem_u32[base + jp2 * 2] = v;
      }
    }
  }
  __syncthreads();

  // ---- stage 2a: read all four rows for (pos, hc) into registers ----
  const int pos = tid & 15;
  const int hc  = tid >> 4;
  float Lr[16], Rr[16], Jl[16], Jr[16];
  {
    float* dsts[4] = {Lr, Rr, Jl, Jr};
    #pragma unroll
    for (int mrow = 0; mrow < 4; ++mrow) {
      int row = mrow * 16 + hc;
      int base = YL(row, pos, 0);
      float* dst = dsts[mrow];
      #pragma unroll
      for (int jp2 = 0; jp2 < 4; ++jp2) {
        uint2 v = *(const uint2*)&smem_u32[base + jp2 * 2];
        dst[4*jp2 + 0] = bflo(v.x); dst[4*jp2 + 1] = bfhi(v.x);
        dst[4*jp2 + 2] = bflo(v.y); dst[4*jp2 + 3] = bfhi(v.y);
      }
    }
  }
  const float rs = ref[(size_t)(P0 + pos) * 16 + 15];
  __syncthreads();   // all yl reads done; buffer is now reusable as hidden

  // ---- stage 2b: channel-local bilinears, write hidden (bf16) ----
  {
    float H[16];
    #pragma unroll
    for (int q = 0; q < 16; ++q) H[q] = 0.f;
    #pragma unroll
    for (int j = 0; j < 16; ++j)
      #pragma unroll
      for (int k = 0; k < 16; ++k)
        if (TBL.gp_sgn[j][k] != 0.0f)
          H[TBL.gp_idx[j][k]] += TBL.gp_sgn[j][k] * Lr[j] * Rr[k];
    #pragma unroll
    for (int j = 0; j < 16; ++j)
      smem_us[pos * 544 + j * 32 + hc] = bf1(H[j]);

    #pragma unroll
    for (int q = 0; q < 16; ++q) { H[q] = 0.f; Jl[q] *= rs; }
    #pragma unroll
    for (int j = 0; j < 16; ++j)
      #pragma unroll
      for (int k = 0; k < 16; ++k)
        if (TBL.jn_sgn[j][k] != 0.0f)
          H[TBL.jn_idx[j][k]] += TBL.jn_sgn[j][k] * Jl[j] * Jr[k];
    #pragma unroll
    for (int j = 0; j < 16; ++j)
      smem_us[pos * 544 + j * 32 + 16 + hc] = bf1(H[j]);
  }
  __syncthreads();

  // ---- stage 3 (waves 0,1): output equi-linear. stage 4 (waves 2,3): scalar head ----
  if (wave < 2) {
    f32x4 zf = {0.f, 0.f, 0.f, 0.f};
    f32x4 a3[16];
    #pragma unroll
    for (int j = 0; j < 16; ++j) a3[j] = zf;
    #pragma unroll
    for (int j = 0; j < 16; ++j) {
      uint4 hv = *(const uint4*)&smem_u32[HL_U32(lm, j, lq * 4)];
      short8 w = __builtin_bit_cast(short8, wpk[(104 + j * 2 + wave) * 64 + lane]);
      a3[j] = MFMA16(w, __builtin_bit_cast(short8, hv), a3[j]);
    }
    #pragma unroll
    for (int m = 0; m < 8; ++m) {
      uint4 hv = *(const uint4*)&smem_u32[HL_U32(lm, E0_SRC[m], lq * 4)];
      short8 w = __builtin_bit_cast(short8, wpk[(104 + (16 + m) * 2 + wave) * 64 + lane]);
      a3[E0_TGT[m]] = MFMA16(w, __builtin_bit_cast(short8, hv), a3[E0_TGT[m]]);
    }
    #pragma unroll
    for (int h = 0; h < 2; ++h) {
      short8 w = __builtin_bit_cast(short8, wpk[(104 + (24 + h) * 2 + wave) * 64 + lane]);
      a3[0] = MFMA16(w, sfrag[h], a3[0]);
    }
    float* ob = out_mv + ((size_t)(P0 + lm)) * 512 + (size_t)(wave * 16 + lq * 4) * 16;
    #pragma unroll
    for (int r = 0; r < 4; ++r) {
      #pragma unroll
      for (int g = 0; g < 4; ++g) {
        *(float4*)(ob + r * 16 + g * 4) =
            make_float4(a3[4*g][r], a3[4*g+1][r], a3[4*g+2][r], a3[4*g+3][r]);
      }
    }
  } else {
    uint4 hv0 = *(const uint4*)&smem_u32[HL_U32(lm, 0, lq * 4)];
    short8 bh0 = __builtin_bit_cast(short8, hv0);
    int w2 = wave - 2;
    f32x4 zf = {0.f, 0.f, 0.f, 0.f};
    #pragma unroll
    for (int t2 = 0; t2 < 2; ++t2) {
      int otg = w2 * 2 + t2;
      f32x4 aS = zf;
      aS = MFMA16(__builtin_bit_cast(short8, wpk[(156 + otg) * 64 + lane]), bh0, aS);
      aS = MFMA16(__builtin_bit_cast(short8, wpk[(160 + otg) * 64 + lane]), sfrag[0], aS);
      aS = MFMA16(__builtin_bit_cast(short8, wpk[(164 + otg) * 64 + lane]), sfrag[1], aS);
      float* osb = out_s + ((size_t)(P0 + lm)) * 64 + otg * 16 + lq * 4;
      *(float4*)osb = make_float4(aS[0], aS[1], aS[2], aS[3]);
    }
  }
}

extern "C" void kernel_launch(void* const* d_in, const int* in_sizes, int n_in,
                              void* d_out, int out_size, void* d_ws, size_t ws_size,
                              hipStream_t stream) {
  (void)in_sizes; (void)n_in; (void)out_size; (void)ws_size;
  const float* mv    = (const float*)d_in[0];
  const float* ref   = (const float*)d_in[1];
  const float* s     = (const float*)d_in[2];
  // d_in[3..5] = basis/gp/jn tables: baked at compile time.
  const float* wlmv  = (const float*)d_in[6];
  const float* wls   = (const float*)d_in[7];
  const float* wrmv  = (const float*)d_in[8];
  const float* wrs   = (const float*)d_in[9];
  const float* wjlmv = (const float*)d_in[10];
  const float* wjls  = (const float*)d_in[11];
  const float* wjrmv = (const float*)d_in[12];
  const float* wjrs  = (const float*)d_in[13];
  const float* womv  = (const float*)d_in[14];
  const float* ws2mv = (const float*)d_in[15];
  const float* wm2s  = (const float*)d_in[16];
  const float* ws2s  = (const float*)d_in[17];

  float* out_mv = (float*)d_out;
  float* out_s  = out_mv + (size_t)NPOS_TOTAL * 32 * 16;
  uint4* wpk = (uint4*)d_ws;

  gb_prep<<<42, 256, 0, stream>>>(wlmv, wrmv, wjlmv, wjrmv, wls, wrs, wjls, wjrs,
                                  womv, ws2mv, wm2s, ws2s, wpk);
  gb_main<<<NPOS_TOTAL / 16, 256, 0, stream>>>(mv, ref, s, wpk, out_mv, out_s);
}